// Round 6
// baseline (369.273 us; speedup 1.0000x reference)
//
#include <hip/hip_runtime.h>
#include <math.h>
#include <float.h>

#define IN_DIM   1024
#define OUT_DIM  128
#define MEM_LEN  131072
#define COPY_GRID 8192
#define DIST_BLOCKS 2048   // 64 rows per block (16 rows/wave * 4 waves)

#define NA_FLOATS  ((long long)MEM_LEN * OUT_DIM)   // 16,777,216
#define NB_FLOATS  ((long long)MEM_LEN * IN_DIM)    // 134,217,728
#define N_TOTAL    (NA_FLOATS + NB_FLOATS)          // 150,994,944
#define NA_CHUNKS  (NA_FLOATS / 4)                  // 4,194,304
#define CMAX       ((N_TOTAL - 4) / 4)              // 37,748,735 last full dst chunk

// insert (v,i) into ascending-(v,i) top-3; lexicographic tie-break matches
// jax.lax.top_k stability (lower index wins on equal distance)
__device__ __forceinline__ void ins3(float v, int i,
    float& v0, int& i0, float& v1, int& i1, float& v2, int& i2) {
  if (v < v0 || (v == v0 && i < i0)) {
    v2 = v1; i2 = i1; v1 = v0; i1 = i0; v0 = v; i0 = i;
  } else if (v < v1 || (v == v1 && i < i1)) {
    v2 = v1; i2 = i1; v1 = v; i1 = i;
  } else if (v < v2 || (v == v2 && i < i2)) {
    v2 = v; i2 = i;
  }
}

// K1: normalize + encoder + decoder-MSE + win_loss. Single block, 1024 threads.
__global__ __launch_bounds__(1024) void k1_encode(
    const float* __restrict__ x, const float* __restrict__ mean,
    const float* __restrict__ stdv, const float* __restrict__ W_enc,
    const float* __restrict__ b_enc, const float* __restrict__ W_dec,
    const float* __restrict__ b_dec, const float* __restrict__ win_mean,
    const float* __restrict__ win_std,
    float* __restrict__ ws_enc, float* __restrict__ ws_winloss) {
  __shared__ float s_new[IN_DIM];
  __shared__ float s_part[8][OUT_DIM];
  __shared__ float s_enc[OUT_DIM];
  __shared__ float s_red[16];
  const int t = threadIdx.x;
  const float sd = stdv[t];
  const float nv = (sd == 0.0f) ? 0.0f : (x[t] - mean[t]) / sd;
  s_new[t] = nv;
  __syncthreads();
  const int o = t & (OUT_DIM - 1);
  const int p = t >> 7;
  float partial = 0.0f;
  #pragma unroll 8
  for (int i = 0; i < 128; ++i) {
    const int k = p * 128 + i;
    partial += s_new[k] * W_enc[k * OUT_DIM + o];
  }
  s_part[p][o] = partial;
  __syncthreads();
  if (t < OUT_DIM) {
    float sum = b_enc[t];
    #pragma unroll
    for (int pp = 0; pp < 8; ++pp) sum += s_part[pp][t];
    const float e = tanhf(sum);
    s_enc[t] = e;
    ws_enc[t] = e;
  }
  __syncthreads();
  float r = b_dec[t];
  #pragma unroll 8
  for (int k = 0; k < OUT_DIM; ++k) r += s_enc[k] * W_dec[k * IN_DIM + t];
  const float diff = r - nv;
  float sq = diff * diff;
  for (int off = 32; off; off >>= 1) sq += __shfl_xor(sq, off, 64);
  const int lane = t & 63, wid = t >> 6;
  if (lane == 0) s_red[wid] = sq;
  __syncthreads();
  if (t == 0) {
    float tot = 0.0f;
    #pragma unroll
    for (int w = 0; w < 16; ++w) tot += s_red[w];
    const float mse = tot / (float)IN_DIM;
    const float z = (mse - win_mean[0]) / win_std[0];
    const float prob = 0.5f * erfcf(-z * 0.70710678118654752440f); // ndtr
    ws_winloss[0] = (1.0f - prob) * mse;  // SKIP_THRESHOLD == 1
  }
}

// K2: L1 distances. float4 loads (2 rows per wave-instruction, 1KB contig),
// 5-level shfl reduce within each 32-lane half, 16 rows per wave.
__global__ __launch_bounds__(256) void k2_dist(
    const float* __restrict__ memory, const float* __restrict__ ws_enc,
    float* __restrict__ topv, int* __restrict__ topi) {
  const int t = threadIdx.x;
  const int lane = t & 63;
  const int wid = t >> 6;
  const int half = lane >> 5;            // row parity within pair
  const int col  = lane & 31;            // float4 column within row
  const float4 e = reinterpret_cast<const float4*>(ws_enc)[col];
  const float4* m4 = reinterpret_cast<const float4*>(memory);
  float v0 = FLT_MAX, v1 = FLT_MAX, v2 = FLT_MAX;
  int i0 = 0x7fffffff, i1 = 0x7fffffff, i2 = 0x7fffffff;
  const int r0 = (blockIdx.x * 4 + wid) * 16;
  for (int rr = 0; rr < 16; rr += 2) {
    const float4 m = m4[(size_t)(r0 + rr) * 32 + lane];
    float d = fabsf(m.x - e.x) + fabsf(m.y - e.y)
            + fabsf(m.z - e.z) + fabsf(m.w - e.w);
    d += __shfl_xor(d, 1, 64);
    d += __shfl_xor(d, 2, 64);
    d += __shfl_xor(d, 4, 64);
    d += __shfl_xor(d, 8, 64);
    d += __shfl_xor(d, 16, 64);          // replicated within each 32-half
    ins3(d, r0 + rr + half, v0, i0, v1, i1, v2, i2);
  }
  // merge the two halves' top3
  {
    const float w0 = __shfl_xor(v0, 32, 64);
    const float w1 = __shfl_xor(v1, 32, 64);
    const float w2 = __shfl_xor(v2, 32, 64);
    const int j0 = __shfl_xor(i0, 32, 64);
    const int j1 = __shfl_xor(i1, 32, 64);
    const int j2 = __shfl_xor(i2, 32, 64);
    ins3(w0, j0, v0, i0, v1, i1, v2, i2);
    ins3(w1, j1, v0, i0, v1, i1, v2, i2);
    ins3(w2, j2, v0, i0, v1, i1, v2, i2);
  }
  __shared__ float sv[4][3];
  __shared__ int   si[4][3];
  if (lane == 0) {
    sv[wid][0] = v0; sv[wid][1] = v1; sv[wid][2] = v2;
    si[wid][0] = i0; si[wid][1] = i1; si[wid][2] = i2;
  }
  __syncthreads();
  if (t == 0) {
    for (int w = 1; w < 4; ++w)
      for (int j = 0; j < 3; ++j)
        ins3(sv[w][j], si[w][j], v0, i0, v1, i1, v2, i2);
    topv[blockIdx.x * 3 + 0] = v0; topi[blockIdx.x * 3 + 0] = i0;
    topv[blockIdx.x * 3 + 1] = v1; topi[blockIdx.x * 3 + 1] = i1;
    topv[blockIdx.x * 3 + 2] = v2; topi[blockIdx.x * 3 + 2] = i2;
  }
}

// Realigned copy, m13-memcpy pattern: dst chunk c (16B-aligned) gets src
// dwords [4c-1, 4c+2] via an UNALIGNED vector load. No cross-lane ops, no
// edge loads; grid-stride with consecutive threads on consecutive chunks
// (1KB contiguous per wave instruction on both sides). The single chunk
// whose source straddles the memory/mem_data boundary (c == NA_CHUNKS)
// takes a scalar path (avoids a 12B OOB read).
__global__ __launch_bounds__(256) void copy_all(
    const float* __restrict__ memory, const float* __restrict__ mem_data,
    float* __restrict__ out) {
  float4* out4 = reinterpret_cast<float4*>(out);
  const long long stride = (long long)gridDim.x * 256;
  long long c = (long long)blockIdx.x * 256 + threadIdx.x + 1;
  #pragma unroll 4
  for (; c <= CMAX; c += stride) {
    float4 v;
    if (__builtin_expect(c == NA_CHUNKS, 0)) {
      v.x = memory[NA_FLOATS - 1];
      v.y = mem_data[0]; v.z = mem_data[1]; v.w = mem_data[2];
    } else {
      const long long s = 4 * c - 1;
      const float* src = (s >= NA_FLOATS) ? (mem_data + (s - NA_FLOATS))
                                          : (memory + s);
      __builtin_memcpy(&v, src, 16);
    }
    out4[c] = v;
  }
  if (blockIdx.x == 0 && threadIdx.x == 0) {
    out[1] = memory[0]; out[2] = memory[1]; out[3] = memory[2];
    out[N_TOTAL] = mem_data[NB_FLOATS - 1];
  }
}

// K3+K4: merge candidates, final loss, conditional FIFO row update.
__global__ __launch_bounds__(1024) void k3_topk_update(
    const float* __restrict__ topv, const int* __restrict__ topi,
    const float* __restrict__ ws_winloss, const float* __restrict__ ws_enc,
    const float* __restrict__ x, float* __restrict__ out_loss,
    float* __restrict__ out_mem, float* __restrict__ out_md) {
  const int t = threadIdx.x;
  const int n = DIST_BLOCKS * 3;   // 6144
  float v0 = FLT_MAX, v1 = FLT_MAX, v2 = FLT_MAX;
  int i0 = 0x7fffffff, i1 = 0x7fffffff, i2 = 0x7fffffff;
  for (int j = t; j < n; j += 1024) ins3(topv[j], topi[j], v0, i0, v1, i1, v2, i2);
  for (int off = 32; off; off >>= 1) {
    const float ov0 = __shfl_xor(v0, off, 64);
    const float ov1 = __shfl_xor(v1, off, 64);
    const float ov2 = __shfl_xor(v2, off, 64);
    const int oi0 = __shfl_xor(i0, off, 64);
    const int oi1 = __shfl_xor(i1, off, 64);
    const int oi2 = __shfl_xor(i2, off, 64);
    ins3(ov0, oi0, v0, i0, v1, i1, v2, i2);
    ins3(ov1, oi1, v0, i0, v1, i1, v2, i2);
    ins3(ov2, oi2, v0, i0, v1, i1, v2, i2);
  }
  __shared__ float sv[16][3];
  __shared__ int   si[16][3];
  __shared__ int s_i0, s_cond;
  const int lane = t & 63, wid = t >> 6;
  if (lane == 0) {
    sv[wid][0] = v0; sv[wid][1] = v1; sv[wid][2] = v2;
    si[wid][0] = i0; si[wid][1] = i1; si[wid][2] = i2;
  }
  __syncthreads();
  if (t == 0) {
    for (int w = 1; w < 16; ++w)
      for (int j = 0; j < 3; ++j)
        ins3(sv[w][j], si[w][j], v0, i0, v1, i1, v2, i2);
    const float loss_values = (v0 + 0.5f * v1 + 0.25f * v2) / 1.75f;
    const float wl = ws_winloss[0];
    out_loss[0] = wl + loss_values;
    s_i0 = i0;
    s_cond = (loss_values <= wl) ? 1 : 0;
  }
  __syncthreads();
  if (s_cond) {
    if (t < OUT_DIM) out_mem[(size_t)s_i0 * OUT_DIM + t] = ws_enc[t];
    out_md[(size_t)s_i0 * IN_DIM + t] = x[t];
  }
}

extern "C" void kernel_launch(void* const* d_in, const int* in_sizes, int n_in,
                              void* d_out, int out_size, void* d_ws, size_t ws_size,
                              hipStream_t stream) {
  const float* x        = (const float*)d_in[0];
  const float* mean     = (const float*)d_in[1];
  const float* stdv     = (const float*)d_in[2];
  const float* memory   = (const float*)d_in[3];
  const float* mem_data = (const float*)d_in[4];
  const float* W_enc    = (const float*)d_in[5];
  const float* b_enc    = (const float*)d_in[6];
  const float* W_dec    = (const float*)d_in[7];
  const float* b_dec    = (const float*)d_in[8];
  const float* win_mean = (const float*)d_in[9];
  const float* win_std  = (const float*)d_in[10];

  float* out      = (float*)d_out;
  float* out_loss = out;
  float* out_mem  = out + 1;
  float* out_md   = out + 1 + (size_t)MEM_LEN * OUT_DIM;

  float* ws        = (float*)d_ws;
  float* ws_enc    = ws;                     // 128
  float* ws_wl     = ws + 128;               // 1 (win_loss)
  float* ws_topv   = ws + 256;               // 6144
  int*   ws_topi   = (int*)(ws + 256 + DIST_BLOCKS * 3);   // 6144

  k1_encode<<<1, 1024, 0, stream>>>(x, mean, stdv, W_enc, b_enc, W_dec, b_dec,
                                    win_mean, win_std, ws_enc, ws_wl);
  k2_dist<<<DIST_BLOCKS, 256, 0, stream>>>(memory, ws_enc, ws_topv, ws_topi);
  copy_all<<<COPY_GRID, 256, 0, stream>>>(memory, mem_data, out);
  k3_topk_update<<<1, 1024, 0, stream>>>(ws_topv, ws_topi, ws_wl, ws_enc, x,
                                         out_loss, out_mem, out_md);
}

// Round 7
// 327.755 us; speedup vs baseline: 1.1267x; 1.1267x over previous
//
#include <hip/hip_runtime.h>
#include <math.h>
#include <float.h>

#define IN_DIM   1024
#define OUT_DIM  128
#define MEM_LEN  131072
#define COPY_GRID 2048     // 2048 blocks * 4 waves = 8192 waves; 18 frames each
#define DIST_BLOCKS 2048   // 64 rows per block (16 rows/wave * 4 waves)

#define NA_FLOATS  ((long long)MEM_LEN * OUT_DIM)   // 16,777,216
#define NB_FLOATS  ((long long)MEM_LEN * IN_DIM)    // 134,217,728
#define N_TOTAL    (NA_FLOATS + NB_FLOATS)          // 150,994,944
#define NFRAMES    (N_TOTAL / 1024)                 // 147,456 4KB output frames
#define FRAME_MEM  16384                            // frames < this source from memory

// insert (v,i) into ascending-(v,i) top-3; lexicographic tie-break matches
// jax.lax.top_k stability (lower index wins on equal distance)
__device__ __forceinline__ void ins3(float v, int i,
    float& v0, int& i0, float& v1, int& i1, float& v2, int& i2) {
  if (v < v0 || (v == v0 && i < i0)) {
    v2 = v1; i2 = i1; v1 = v0; i1 = i0; v0 = v; i0 = i;
  } else if (v < v1 || (v == v1 && i < i1)) {
    v2 = v1; i2 = i1; v1 = v; i1 = i;
  } else if (v < v2 || (v == v2 && i < i2)) {
    v2 = v; i2 = i;
  }
}

// K1: normalize + encoder + decoder-MSE + win_loss. Single block, 1024 threads.
__global__ __launch_bounds__(1024) void k1_encode(
    const float* __restrict__ x, const float* __restrict__ mean,
    const float* __restrict__ stdv, const float* __restrict__ W_enc,
    const float* __restrict__ b_enc, const float* __restrict__ W_dec,
    const float* __restrict__ b_dec, const float* __restrict__ win_mean,
    const float* __restrict__ win_std,
    float* __restrict__ ws_enc, float* __restrict__ ws_winloss) {
  __shared__ float s_new[IN_DIM];
  __shared__ float s_part[8][OUT_DIM];
  __shared__ float s_enc[OUT_DIM];
  __shared__ float s_red[16];
  const int t = threadIdx.x;
  const float sd = stdv[t];
  const float nv = (sd == 0.0f) ? 0.0f : (x[t] - mean[t]) / sd;
  s_new[t] = nv;
  __syncthreads();
  const int o = t & (OUT_DIM - 1);
  const int p = t >> 7;
  float partial = 0.0f;
  #pragma unroll 8
  for (int i = 0; i < 128; ++i) {
    const int k = p * 128 + i;
    partial += s_new[k] * W_enc[k * OUT_DIM + o];
  }
  s_part[p][o] = partial;
  __syncthreads();
  if (t < OUT_DIM) {
    float sum = b_enc[t];
    #pragma unroll
    for (int pp = 0; pp < 8; ++pp) sum += s_part[pp][t];
    const float e = tanhf(sum);
    s_enc[t] = e;
    ws_enc[t] = e;
  }
  __syncthreads();
  float r = b_dec[t];
  #pragma unroll 8
  for (int k = 0; k < OUT_DIM; ++k) r += s_enc[k] * W_dec[k * IN_DIM + t];
  const float diff = r - nv;
  float sq = diff * diff;
  for (int off = 32; off; off >>= 1) sq += __shfl_xor(sq, off, 64);
  const int lane = t & 63, wid = t >> 6;
  if (lane == 0) s_red[wid] = sq;
  __syncthreads();
  if (t == 0) {
    float tot = 0.0f;
    #pragma unroll
    for (int w = 0; w < 16; ++w) tot += s_red[w];
    const float mse = tot / (float)IN_DIM;
    const float z = (mse - win_mean[0]) / win_std[0];
    const float prob = 0.5f * erfcf(-z * 0.70710678118654752440f); // ndtr
    ws_winloss[0] = (1.0f - prob) * mse;  // SKIP_THRESHOLD == 1
  }
}

// K2: L1 distances. float4 loads (2 rows per wave-instruction, 1KB contig),
// 5-level shfl reduce within each 32-lane half, 16 rows per wave.
__global__ __launch_bounds__(256) void k2_dist(
    const float* __restrict__ memory, const float* __restrict__ ws_enc,
    float* __restrict__ topv, int* __restrict__ topi) {
  const int t = threadIdx.x;
  const int lane = t & 63;
  const int wid = t >> 6;
  const int half = lane >> 5;            // row parity within pair
  const int col  = lane & 31;            // float4 column within row
  const float4 e = reinterpret_cast<const float4*>(ws_enc)[col];
  const float4* m4 = reinterpret_cast<const float4*>(memory);
  float v0 = FLT_MAX, v1 = FLT_MAX, v2 = FLT_MAX;
  int i0 = 0x7fffffff, i1 = 0x7fffffff, i2 = 0x7fffffff;
  const int r0 = (blockIdx.x * 4 + wid) * 16;
  for (int rr = 0; rr < 16; rr += 2) {
    const float4 m = m4[(size_t)(r0 + rr) * 32 + lane];
    float d = fabsf(m.x - e.x) + fabsf(m.y - e.y)
            + fabsf(m.z - e.z) + fabsf(m.w - e.w);
    d += __shfl_xor(d, 1, 64);
    d += __shfl_xor(d, 2, 64);
    d += __shfl_xor(d, 4, 64);
    d += __shfl_xor(d, 8, 64);
    d += __shfl_xor(d, 16, 64);          // replicated within each 32-half
    ins3(d, r0 + rr + half, v0, i0, v1, i1, v2, i2);
  }
  // merge the two halves' top3
  {
    const float w0 = __shfl_xor(v0, 32, 64);
    const float w1 = __shfl_xor(v1, 32, 64);
    const float w2 = __shfl_xor(v2, 32, 64);
    const int j0 = __shfl_xor(i0, 32, 64);
    const int j1 = __shfl_xor(i1, 32, 64);
    const int j2 = __shfl_xor(i2, 32, 64);
    ins3(w0, j0, v0, i0, v1, i1, v2, i2);
    ins3(w1, j1, v0, i0, v1, i1, v2, i2);
    ins3(w2, j2, v0, i0, v1, i1, v2, i2);
  }
  __shared__ float sv[4][3];
  __shared__ int   si[4][3];
  if (lane == 0) {
    sv[wid][0] = v0; sv[wid][1] = v1; sv[wid][2] = v2;
    si[wid][0] = i0; si[wid][1] = i1; si[wid][2] = i2;
  }
  __syncthreads();
  if (t == 0) {
    for (int w = 1; w < 4; ++w)
      for (int j = 0; j < 3; ++j)
        ins3(sv[w][j], si[w][j], v0, i0, v1, i1, v2, i2);
    topv[blockIdx.x * 3 + 0] = v0; topi[blockIdx.x * 3 + 0] = i0;
    topv[blockIdx.x * 3 + 1] = v1; topi[blockIdx.x * 3 + 1] = i1;
    topv[blockIdx.x * 3 + 2] = v2; topi[blockIdx.x * 3 + 2] = i2;
  }
}

// Realigned copy, FRAME-ALIGNED: wave handles 4KB output frames
// [4096*s, 4096*(s+1)). out dword j = src dword j-1 (src = memory++mem_data);
// out[0] gets garbage here and is overwritten by k3 (loss) afterwards.
// Per frame: 4 aligned contiguous 1KB loads, 4 aligned contiguous 1KB
// FULL-LINE stores, realign via 4 shfl_up + 3 broadcast shfl + 1 broadcast
// edge dword. NA_FLOATS = 1024*16384 -> no frame straddles the region
// boundary; no slow path.
__global__ __launch_bounds__(256) void copy_all(
    const float* __restrict__ memory, const float* __restrict__ mem_data,
    float* __restrict__ out) {
  const int t = threadIdx.x;
  const int lane = t & 63;
  const int wid  = t >> 6;
  const float4* mem4 = reinterpret_cast<const float4*>(memory);
  const float4* md4  = reinterpret_cast<const float4*>(mem_data);
  float4* out4 = reinterpret_cast<float4*>(out);
  const long long wstride = (long long)gridDim.x * 4;
  for (long long s = (long long)blockIdx.x * 4 + wid; s < NFRAMES; s += wstride) {
    const float4* src4 = (s < FRAME_MEM) ? (mem4 + (s << 8))
                                         : (md4 + ((s - FRAME_MEM) << 8));
    float edge = 0.0f;
    if (s > 0) {
      const long long sd = (s << 10) - 1;      // src dword preceding the frame
      edge = (sd < NA_FLOATS) ? memory[sd] : mem_data[sd - NA_FLOATS];
    }
    const float4 a0 = src4[lane];
    const float4 a1 = src4[lane + 64];
    const float4 a2 = src4[lane + 128];
    const float4 a3 = src4[lane + 192];
    float p0 = __shfl_up(a0.w, 1, 64);
    float p1 = __shfl_up(a1.w, 1, 64);
    float p2 = __shfl_up(a2.w, 1, 64);
    float p3 = __shfl_up(a3.w, 1, 64);
    const float t1 = __shfl(a0.w, 63, 64);
    const float t2 = __shfl(a1.w, 63, 64);
    const float t3 = __shfl(a2.w, 63, 64);
    if (lane == 0) { p0 = edge; p1 = t1; p2 = t2; p3 = t3; }
    float4* ob = out4 + (s << 8);
    ob[lane]       = make_float4(p0, a0.x, a0.y, a0.z);
    ob[lane + 64]  = make_float4(p1, a1.x, a1.y, a1.z);
    ob[lane + 128] = make_float4(p2, a2.x, a2.y, a2.z);
    ob[lane + 192] = make_float4(p3, a3.x, a3.y, a3.z);
  }
  if (blockIdx.x == 0 && t == 0)
    out[N_TOTAL] = mem_data[NB_FLOATS - 1];
}

// K3+K4: merge candidates, final loss (overwrites out[0] garbage from the
// copy), conditional FIFO row update.
__global__ __launch_bounds__(1024) void k3_topk_update(
    const float* __restrict__ topv, const int* __restrict__ topi,
    const float* __restrict__ ws_winloss, const float* __restrict__ ws_enc,
    const float* __restrict__ x, float* __restrict__ out_loss,
    float* __restrict__ out_mem, float* __restrict__ out_md) {
  const int t = threadIdx.x;
  const int n = DIST_BLOCKS * 3;   // 6144
  float v0 = FLT_MAX, v1 = FLT_MAX, v2 = FLT_MAX;
  int i0 = 0x7fffffff, i1 = 0x7fffffff, i2 = 0x7fffffff;
  for (int j = t; j < n; j += 1024) ins3(topv[j], topi[j], v0, i0, v1, i1, v2, i2);
  for (int off = 32; off; off >>= 1) {
    const float ov0 = __shfl_xor(v0, off, 64);
    const float ov1 = __shfl_xor(v1, off, 64);
    const float ov2 = __shfl_xor(v2, off, 64);
    const int oi0 = __shfl_xor(i0, off, 64);
    const int oi1 = __shfl_xor(i1, off, 64);
    const int oi2 = __shfl_xor(i2, off, 64);
    ins3(ov0, oi0, v0, i0, v1, i1, v2, i2);
    ins3(ov1, oi1, v0, i0, v1, i1, v2, i2);
    ins3(ov2, oi2, v0, i0, v1, i1, v2, i2);
  }
  __shared__ float sv[16][3];
  __shared__ int   si[16][3];
  __shared__ int s_i0, s_cond;
  const int lane = t & 63, wid = t >> 6;
  if (lane == 0) {
    sv[wid][0] = v0; sv[wid][1] = v1; sv[wid][2] = v2;
    si[wid][0] = i0; si[wid][1] = i1; si[wid][2] = i2;
  }
  __syncthreads();
  if (t == 0) {
    for (int w = 1; w < 16; ++w)
      for (int j = 0; j < 3; ++j)
        ins3(sv[w][j], si[w][j], v0, i0, v1, i1, v2, i2);
    const float loss_values = (v0 + 0.5f * v1 + 0.25f * v2) / 1.75f;
    const float wl = ws_winloss[0];
    out_loss[0] = wl + loss_values;
    s_i0 = i0;
    s_cond = (loss_values <= wl) ? 1 : 0;
  }
  __syncthreads();
  if (s_cond) {
    if (t < OUT_DIM) out_mem[(size_t)s_i0 * OUT_DIM + t] = ws_enc[t];
    out_md[(size_t)s_i0 * IN_DIM + t] = x[t];
  }
}

extern "C" void kernel_launch(void* const* d_in, const int* in_sizes, int n_in,
                              void* d_out, int out_size, void* d_ws, size_t ws_size,
                              hipStream_t stream) {
  const float* x        = (const float*)d_in[0];
  const float* mean     = (const float*)d_in[1];
  const float* stdv     = (const float*)d_in[2];
  const float* memory   = (const float*)d_in[3];
  const float* mem_data = (const float*)d_in[4];
  const float* W_enc    = (const float*)d_in[5];
  const float* b_enc    = (const float*)d_in[6];
  const float* W_dec    = (const float*)d_in[7];
  const float* b_dec    = (const float*)d_in[8];
  const float* win_mean = (const float*)d_in[9];
  const float* win_std  = (const float*)d_in[10];

  float* out      = (float*)d_out;
  float* out_loss = out;
  float* out_mem  = out + 1;
  float* out_md   = out + 1 + (size_t)MEM_LEN * OUT_DIM;

  float* ws        = (float*)d_ws;
  float* ws_enc    = ws;                     // 128
  float* ws_wl     = ws + 128;               // 1 (win_loss)
  float* ws_topv   = ws + 256;               // 6144
  int*   ws_topi   = (int*)(ws + 256 + DIST_BLOCKS * 3);   // 6144

  k1_encode<<<1, 1024, 0, stream>>>(x, mean, stdv, W_enc, b_enc, W_dec, b_dec,
                                    win_mean, win_std, ws_enc, ws_wl);
  k2_dist<<<DIST_BLOCKS, 256, 0, stream>>>(memory, ws_enc, ws_topv, ws_topi);
  copy_all<<<COPY_GRID, 256, 0, stream>>>(memory, mem_data, out);
  k3_topk_update<<<1, 1024, 0, stream>>>(ws_topv, ws_topi, ws_wl, ws_enc, x,
                                         out_loss, out_mem, out_md);
}